// Round 6
// baseline (209.886 us; speedup 1.0000x reference)
//
#include <hip/hip_runtime.h>
#include <stdint.h>

namespace {

constexpr int kB = 256;
constexpr int kV = 128000;
constexpr int kBlk = 256;
constexpr int kSubs = 5;                  // blocks per row
constexpr int kSpan = kV / kSubs;         // 25600 floats per block
constexpr int kF4 = 5;                    // float4s per thread per tile
constexpr int kTile = kBlk * 4 * kF4;     // 5120 floats
constexpr int kTiles = kSpan / kTile;     // 5 tiles per block

struct Part { float val; int idx; };

// JAX threefry2x32, key = (0, 42). Partitionable mode: bits[i] = o0 ^ o1 of
// threefry(x0=hi32(i)=0, x1=i). Bit-exact vs reference (absmax = 0, R1-R5).
__device__ __forceinline__ uint32_t threefry_bits(uint32_t x1) {
  constexpr uint32_t ks0 = 0u;
  constexpr uint32_t ks1 = 42u;
  constexpr uint32_t ks2 = 0x1BD11BDAu ^ ks0 ^ ks1;
  uint32_t x0 = ks0;
  x1 += ks1;
#define TF_ROUND(r) { x0 += x1; x1 = __builtin_rotateleft32(x1, r); x1 ^= x0; }
  TF_ROUND(13) TF_ROUND(15) TF_ROUND(26) TF_ROUND(6)
  x0 += ks1; x1 += ks2 + 1u;
  TF_ROUND(17) TF_ROUND(29) TF_ROUND(16) TF_ROUND(24)
  x0 += ks2; x1 += ks0 + 2u;
  TF_ROUND(13) TF_ROUND(15) TF_ROUND(26) TF_ROUND(6)
  x0 += ks0; x1 += ks1 + 3u;
  TF_ROUND(17) TF_ROUND(29) TF_ROUND(16) TF_ROUND(24)
  x0 += ks1; x1 += ks2 + 4u;
  TF_ROUND(13) TF_ROUND(15) TF_ROUND(26) TF_ROUND(6)
  x0 += ks2; x1 += ks0 + 5u;
#undef TF_ROUND
  return x0 ^ x1;
}

// gumbel = -ln(-ln(f + tiny)), f = bitcast(bits>>9 | 0x3f800000) - 1.
// Native v_log_f32 * -ln2; bit-stable vs reference across R2-R5 (absmax 0).
__device__ __forceinline__ float gumbel_from_bits(uint32_t bits) {
  constexpr float kTiny = 1.17549435e-38f;  // FLT_MIN
  constexpr float kNegLn2 = -0.69314718055994530942f;
  float f = __uint_as_float((bits >> 9) | 0x3F800000u) - 1.0f;
  float u = f + kTiny;
  float y = __builtin_amdgcn_logf(u) * kNegLn2;   // -ln(u)
  return __builtin_amdgcn_logf(y) * kNegLn2;      // -ln(-ln(u))
}

__global__ __launch_bounds__(kBlk) void sampler_partial(
    const float* __restrict__ logits, const float* __restrict__ temps,
    Part* __restrict__ parts) {
  const int r = blockIdx.x / kSubs;
  const int s = blockIdx.x % kSubs;
  const float t = temps[r];
  const float* __restrict__ row = logits + (size_t)r * kV + (size_t)s * kSpan;
  const int toff = (int)threadIdx.x * 4;  // this thread's slot in a 1024-float slab

  // Register double buffer, fenced with sched_barrier(0) so the scheduler
  // cannot sink the prefetch loads (R5 post-mortem: VGPR_Count=32 proved the
  // compiler deleted the buffer and serialized load->wait->compute).
  float4 cur[kF4], nxt[kF4];

#define LOAD_TILE(dst, k)                                                     \
  {                                                                           \
    const float* g_ = row + (k) * kTile + toff;                               \
    _Pragma("unroll")                                                         \
    for (int i_ = 0; i_ < kF4; ++i_)                                          \
      dst[i_] = *reinterpret_cast<const float4*>(g_ + i_ * kBlk * 4);         \
  }

  float best = -__builtin_inff();
  int bi = 0;

  LOAD_TILE(cur, 0)

  if (t == 0.0f) {
    // greedy: argmax of raw logits, first-occurrence tie-break (strict >;
    // per-thread scan order strictly ascending in element index).
#pragma unroll 1
    for (int k = 0; k < kTiles; ++k) {
      __builtin_amdgcn_sched_barrier(0);
      if (k + 1 < kTiles) LOAD_TILE(nxt, k + 1)
      __builtin_amdgcn_sched_barrier(0);
      const int ebase = s * kSpan + k * kTile + toff;  // index within row
#pragma unroll
      for (int i = 0; i < kF4; ++i) {
        const int v = ebase + i * kBlk * 4;
        float la[4] = {cur[i].x, cur[i].y, cur[i].z, cur[i].w};
#pragma unroll
        for (int j = 0; j < 4; ++j) {
          if (la[j] > best) { best = la[j]; bi = v + j; }
        }
      }
      __builtin_amdgcn_sched_barrier(0);
#pragma unroll
      for (int i = 0; i < kF4; ++i) cur[i] = nxt[i];
    }
  } else {
    // argmax(la/t + g) == argmax(la + t*g) for t > 0 (monotonic, real arith).
#pragma unroll 1
    for (int k = 0; k < kTiles; ++k) {
      __builtin_amdgcn_sched_barrier(0);
      if (k + 1 < kTiles) LOAD_TILE(nxt, k + 1)
      __builtin_amdgcn_sched_barrier(0);
      const int ebase = s * kSpan + k * kTile + toff;
#pragma unroll
      for (int i = 0; i < kF4; ++i) {
        const int v = ebase + i * kBlk * 4;
        const uint32_t base = (uint32_t)(r * kV + v);  // flat index < 2^25
        float la[4] = {cur[i].x, cur[i].y, cur[i].z, cur[i].w};
#pragma unroll
        for (int j = 0; j < 4; ++j) {
          float gb = gumbel_from_bits(threefry_bits(base + (uint32_t)j));
          float key = fmaf(t, gb, la[j]);
          if (key > best) { best = key; bi = v + j; }
        }
      }
      __builtin_amdgcn_sched_barrier(0);
#pragma unroll
      for (int i = 0; i < kF4; ++i) cur[i] = nxt[i];
    }
  }
#undef LOAD_TILE

  __shared__ float sv[kBlk];
  __shared__ int si[kBlk];
  sv[threadIdx.x] = best;
  si[threadIdx.x] = bi;
  __syncthreads();
  for (int st = kBlk / 2; st > 0; st >>= 1) {
    if ((int)threadIdx.x < st) {
      float ov = sv[threadIdx.x + st]; int oi = si[threadIdx.x + st];
      float mv = sv[threadIdx.x];      int mi = si[threadIdx.x];
      if (ov > mv || (ov == mv && oi < mi)) {
        sv[threadIdx.x] = ov; si[threadIdx.x] = oi;
      }
    }
    __syncthreads();
  }
  if (threadIdx.x == 0) {
    parts[r * kSubs + s].val = sv[0];
    parts[r * kSubs + s].idx = si[0];
  }
}

__global__ __launch_bounds__(kB) void sampler_final(
    const Part* __restrict__ parts, int* __restrict__ out) {
  const int r = threadIdx.x;
  if (r < kB) {
    float bv = -__builtin_inff();
    int bi = 0;
#pragma unroll
    for (int g = 0; g < kSubs; ++g) {
      Part p = parts[r * kSubs + g];
      // sub-blocks cover ascending index ranges: strict > + tie -> min idx
      if (p.val > bv || (p.val == bv && p.idx < bi)) { bv = p.val; bi = p.idx; }
    }
    out[r] = bi;
  }
}

}  // namespace

extern "C" void kernel_launch(void* const* d_in, const int* in_sizes, int n_in,
                              void* d_out, int out_size, void* d_ws, size_t ws_size,
                              hipStream_t stream) {
  const float* logits = (const float*)d_in[0];
  const float* temps = (const float*)d_in[1];
  int* out = (int*)d_out;
  Part* parts = (Part*)d_ws;  // kB * kSubs * 8 B = 10 KiB

  sampler_partial<<<dim3(kB * kSubs), dim3(kBlk), 0, stream>>>(logits, temps, parts);
  sampler_final<<<dim3(1), dim3(kB), 0, stream>>>(parts, out);
}